// Round 4
// baseline (366.609 us; speedup 1.0000x reference)
//
#include <hip/hip_runtime.h>
#include <math.h>
#include <stdint.h>

#define D_    768
#define B_    16
#define S_    1024
#define M_    16
#define SM_   1040           // S + M
#define SMP_  1088           // padded kv length (17*64) for PV K-loop
#define SCALE_ 0.036084392f  // 1/sqrt(768)

typedef __bf16 bf16;
typedef __attribute__((ext_vector_type(8))) __bf16 bf16x8;
typedef __attribute__((ext_vector_type(4))) __bf16 bf16x4;
typedef __attribute__((ext_vector_type(4))) float  f32x4;

// async global->LDS, 16B per lane; LDS dest = wave-uniform base + lane*16
#define GL16(gp, lp) __builtin_amdgcn_global_load_lds( \
    (const __attribute__((address_space(1))) void*)(gp), \
    (__attribute__((address_space(3))) void*)(lp), 16, 0, 0)

// ---------------------------------------------------------------------------
// NT GEMM, 128x128 tile, BK=32, bf16 MFMA 16x16x32, 4 waves (2x2), 4x4 frags.
// C[row, col] = sum_k A[row,k] * B[col,k]
//
// Pipelined K-loop (T3-minimum, depth 2): 3 LDS buffers (48 KB -> still
// 3 blocks/CU). Per step: vmcnt(4) [stage(t) landed, stage(t+1) in flight]
// -> s_barrier -> ds_read frags(buf t%3) -> issue stage(t+2) -> 16 MFMA.
// One barrier + one counted vmcnt per 32-K step; never vmcnt(0) in steady
// state, so stage latency (~600-900cy) is covered by ~2 steps of compute.
// Anti-WAR: buf[(t+2)%3] was last read at step t-1, sealed by barrier(t).
//
// LDS rows are 64 B (4 chunks of 16 B); chunk c holds global chunk
// c ^ ((row>>1)&3) (pre-swizzled global source, linear LDS dest per
// gload_lds constraint). Fragment read chunk = lq ^ ((row>>1)&3): the wave
// reads each 16-row x 64 B region exactly once -> 2-way bank aliasing (free).
//
// GM: 1 = flat XCD-swizzled scores (8 row x 9 col x 16 z; xcd owns 2 batches)
//     2 = flat XCD-swizzled PV (8 x 6 x 16)
//     3 = m204-bijective XCD-chunked, col-fast within chunk (QKV / proj)
//
// OUTMODE 1: fp32 row-major + bias (aux).
// OUTMODE 3: fused QKV. B=[wq*SCALE; wk; wv] (2304 rows), wsel=col0/768,
//   bias=aux (bqkv, bq pre-scaled). Q->Cout[b,t<1024,:] bf16;
//   K->C2 [16640,768] bf16; V->C3 Vt[b,e,t] (ldc 1088) bf16x4.
// OUTMODE 4: probs epilogue. P = bf16(exp(acc) * emask[t,col]) for col<1040,
//   0 for pad cols [1040,1088); per-row partial sums -> atomicAdd rsum (=C2).
// OUTMODE 5: PV epilogue: out = bf16(acc / rsum[z*1024+row]) (rsum = aux).
// ---------------------------------------------------------------------------
template<int OUTMODE, int GM>
__launch_bounds__(256, 3)
__global__ void gemm_k(const bf16*  __restrict__ Am,
                       const bf16*  __restrict__ Bm,
                       const float* __restrict__ aux,
                       void* __restrict__ Cout,
                       void* __restrict__ C2,
                       void* __restrict__ C3,
                       int lda, int ldb, int ldc,
                       int K, int colsB,
                       long sA, long sB, long sC)
{
    __shared__ __attribute__((aligned(16))) bf16 As[3 * 128 * 32];
    __shared__ __attribute__((aligned(16))) bf16 Bs[3 * 128 * 32];

    const int t    = threadIdx.x;
    const int l    = t & 63;
    const int wv   = t >> 6;

    int row0, col0, z;
    if (GM == 1) {
        const int bid = blockIdx.x;           // 1152 blocks
        const int xcd = bid & 7, s = bid >> 3;
        z = xcd * 2 + s / 72;
        const int r = s % 72;
        row0 = (r & 7) * 128; col0 = (r >> 3) * 128;
    } else if (GM == 2) {
        const int bid = blockIdx.x;           // 768 blocks
        const int xcd = bid & 7, s = bid >> 3;
        z = xcd * 2 + s / 48;
        const int r = s % 48;
        row0 = (r & 7) * 128; col0 = (r >> 3) * 128;
    } else {
        // m204 bijective XCD chunking: xcd = bid%8 owns a contiguous wg run
        const int gx  = gridDim.x;
        const int nwg = gx * gridDim.y;
        const int bid = blockIdx.y * gx + blockIdx.x;
        const int qn  = nwg >> 3, rr = nwg & 7;
        const int xcd = bid & 7,  idx = bid >> 3;
        const int wg  = (xcd < rr ? xcd * (qn + 1)
                                  : rr * (qn + 1) + (xcd - rr) * qn) + idx;
        row0 = (wg / gx) * 128; col0 = (wg % gx) * 128; z = 0;
    }

    // staging decomposition: per GL16 round, lane l covers row l>>2, chunk l&3
    // of a 64-row half; q in {0,1} selects the half. Source chunk pre-swizzled.
    const int rSt = wv * 16 + (l >> 2);       // staging row for q=0
    const int cSt = l & 3;
    const bf16* aSt[2];
    const bf16* bSt[2];
    #pragma unroll
    for (int q = 0; q < 2; ++q) {
        const int rL = rSt + q * 64;
        const int sc = cSt ^ ((rL >> 1) & 3);
        aSt[q] = Am + (size_t)z * sA + (size_t)(row0 + rL) * lda + sc * 8;
        int bc = col0 + rL;
        if (bc > colsB - 1) bc = colsB - 1;
        bSt[q] = Bm + (size_t)z * sB + (size_t)bc * ldb + sc * 8;
    }

    auto stage = [&](int buf, int kt) {
        #pragma unroll
        for (int q = 0; q < 2; ++q)
            GL16(aSt[q] + kt, &As[buf * 4096 + q * 2048 + wv * 512]);
        #pragma unroll
        for (int q = 0; q < 2; ++q)
            GL16(bSt[q] + kt, &Bs[buf * 4096 + q * 2048 + wv * 512]);
    };

    f32x4 acc[4][4];
    #pragma unroll
    for (int i = 0; i < 4; ++i)
        #pragma unroll
        for (int j = 0; j < 4; ++j)
            acc[i][j] = (f32x4){0.f, 0.f, 0.f, 0.f};

    const int wr0 = (wv & 1) * 64;
    const int wc0 = (wv >> 1) * 64;
    const int lq  = l >> 4;
    const int lm  = l & 15;

    const int nT = K >> 5;         // 32-K steps (all K multiples of 32)
    int br = 0, bw = 2;            // read buf (t%3), write buf ((t+2)%3)

    stage(0, 0);                   // prologue: depth-2 prefetch
    stage(1, 32);

    for (int tt = 0; tt < nT; ++tt) {
        if (tt < nT - 1) asm volatile("s_waitcnt vmcnt(4)" ::: "memory");
        else             asm volatile("s_waitcnt vmcnt(0)" ::: "memory");
        __builtin_amdgcn_s_barrier();

        bf16x8 af[4], bfr[4];
        #pragma unroll
        for (int i = 0; i < 4; ++i) {
            const int rowA = wr0 + i * 16 + lm;
            const int p = lq ^ ((rowA >> 1) & 3);
            af[i] = *(const bf16x8*)&As[br * 4096 + rowA * 32 + p * 8];
        }
        #pragma unroll
        for (int j = 0; j < 4; ++j) {
            const int rowB = wc0 + j * 16 + lm;
            const int p = lq ^ ((rowB >> 1) & 3);
            bfr[j] = *(const bf16x8*)&Bs[br * 4096 + rowB * 32 + p * 8];
        }

        if (tt + 2 < nT) stage(bw, (tt + 2) << 5);

        #pragma unroll
        for (int i = 0; i < 4; ++i)
            #pragma unroll
            for (int j = 0; j < 4; ++j)
                acc[i][j] = __builtin_amdgcn_mfma_f32_16x16x32_bf16(
                    af[i], bfr[j], acc[i][j], 0, 0, 0);

        br = (br == 2) ? 0 : br + 1;
        bw = (bw == 2) ? 0 : bw + 1;
    }

    // epilogue: C/D layout col=lane&15, row=quad*4+reg (m89/m91 verified)
    if (OUTMODE == 4) {
        // probs + fused row-sum atomics
        const bf16* em = (const bf16*)C3;
        float* rsum = (float*)C2;
        #pragma unroll
        for (int i = 0; i < 4; ++i) {
            const int t0 = row0 + wr0 + i * 16 + lq * 4;
            #pragma unroll
            for (int r = 0; r < 4; ++r) {
                float part = 0.f;
                #pragma unroll
                for (int j = 0; j < 4; ++j) {
                    const int gcol = col0 + wc0 + j * 16 + lm;
                    float val = 0.f;
                    if (gcol < SM_)
                        val = __expf(acc[i][j][r])
                            * (float)em[(size_t)(t0 + r) * SM_ + gcol];
                    const bf16 vb = (bf16)val;
                    part += (float)vb;
                    if (gcol < SMP_)
                        ((bf16*)Cout)[(size_t)z * sC
                            + (size_t)(t0 + r) * ldc + gcol] = vb;
                }
                // reduce over the 16 lm lanes (lane bits 0..3)
                #pragma unroll
                for (int o = 8; o; o >>= 1) part += __shfl_xor(part, o);
                if (lm == 0)
                    atomicAdd(&rsum[z * S_ + t0 + r], part);
            }
        }
        return;
    }

    float rin[4][4];
    if (OUTMODE == 5) {
        #pragma unroll
        for (int i = 0; i < 4; ++i) {
            const int t0 = row0 + wr0 + i * 16 + lq * 4;
            #pragma unroll
            for (int r = 0; r < 4; ++r)
                rin[i][r] = 1.f / aux[z * S_ + t0 + r];
        }
    }

    const int wsel = (OUTMODE == 3) ? (col0 / 768) : 0;
    #pragma unroll
    for (int j = 0; j < 4; ++j) {
        const int gcol = col0 + wc0 + j * 16 + lm;
        #pragma unroll
        for (int i = 0; i < 4; ++i) {
            const int t0 = row0 + wr0 + i * 16 + lq * 4;  // 4-aligned
            if (OUTMODE == 3) {
                const int lcol = gcol - wsel * 768;
                const float bv = aux[gcol];
                const int b  = t0 / SM_;
                const int tt = t0 - b * SM_;
                if (wsel == 0) {             // Q -> [B,1024,768] bf16
                    if (tt < S_) {
                        #pragma unroll
                        for (int r = 0; r < 4; ++r)
                            ((bf16*)Cout)[((size_t)b * S_ + tt + r) * D_ + lcol]
                                = (bf16)(acc[i][j][r] + bv);
                    }
                } else if (wsel == 1) {      // K -> [16640,768] bf16
                    #pragma unroll
                    for (int r = 0; r < 4; ++r)
                        ((bf16*)C2)[(size_t)(t0 + r) * D_ + lcol]
                            = (bf16)(acc[i][j][r] + bv);
                } else {                     // V -> Vt[b, e, t] bf16x4
                    bf16x4 o;
                    #pragma unroll
                    for (int r = 0; r < 4; ++r) o[r] = (bf16)(acc[i][j][r] + bv);
                    *(bf16x4*)((bf16*)C3 +
                        ((size_t)b * D_ + lcol) * SMP_ + tt) = o;
                }
            } else if (OUTMODE == 5) {       // PV, normalize by row sum
                #pragma unroll
                for (int r = 0; r < 4; ++r)
                    ((bf16*)Cout)[(size_t)z * sC + (size_t)(t0 + r) * ldc + gcol]
                        = (bf16)(acc[i][j][r] * rin[i][r]);
            } else {                         // OUTMODE 1: fp32 + bias
                if (gcol < colsB) {
                    const float bv = aux ? aux[gcol] : 0.f;
                    #pragma unroll
                    for (int r = 0; r < 4; ++r)
                        ((float*)Cout)[(size_t)z * sC
                            + (size_t)(t0 + r) * ldc + gcol]
                            = acc[i][j][r] + bv;
                }
            }
        }
    }
}

// ---------------------------------------------------------------------------
// Weight cast: [wq*SCALE; wk; wv] -> wqkv [2304,768] bf16, wo -> wob
// ---------------------------------------------------------------------------
__global__ void castw4_k(const float* __restrict__ w0, const float* __restrict__ w1,
                         const float* __restrict__ w2, const float* __restrict__ w3,
                         bf16* __restrict__ wqkv, bf16* __restrict__ wob)
{
    const float* in;
    bf16* out;
    float sc = 1.f;
    const size_t NW = (size_t)D_ * D_;
    switch (blockIdx.y) {
        case 0: in = w0; out = wqkv;          sc = SCALE_; break;
        case 1: in = w1; out = wqkv + NW;     break;
        case 2: in = w2; out = wqkv + 2 * NW; break;
        default: in = w3; out = wob;          break;
    }
    const int i = blockIdx.x * blockDim.x + threadIdx.x;   // float4 chunks
    const float4 f = ((const float4*)in)[i];
    bf16x4 v;
    v[0] = (bf16)(f.x * sc); v[1] = (bf16)(f.y * sc);
    v[2] = (bf16)(f.z * sc); v[3] = (bf16)(f.w * sc);
    ((bf16x4*)out)[i] = v;
}

// ---------------------------------------------------------------------------
// emask[t, col] = bf16(exp(mask[t, col]))   (1024 x 1040)
// ---------------------------------------------------------------------------
__global__ void emask_k(const float* __restrict__ mask, bf16* __restrict__ em)
{
    const int i = blockIdx.x * blockDim.x + threadIdx.x;  // float4 chunks
    const float4 f = ((const float4*)mask)[i];
    bf16x4 v;
    v[0] = (bf16)__expf(f.x); v[1] = (bf16)__expf(f.y);
    v[2] = (bf16)__expf(f.z); v[3] = (bf16)__expf(f.w);
    ((bf16x4*)em)[i] = v;
}

// ---------------------------------------------------------------------------
// cstream[b*1040 + t][e] = bf16( t<1024 ? x[b,t,e] : mem[t-1024,e] )
// Block 6240: concat bq*SCALE|bk|bv into bqkv [2304] and zero rsum [16384].
// ---------------------------------------------------------------------------
__global__ void castx_k(const float* __restrict__ x, const float* __restrict__ mem,
                        bf16* __restrict__ cs,
                        const float* __restrict__ bq, const float* __restrict__ bk,
                        const float* __restrict__ bv, float* __restrict__ bqkv,
                        float* __restrict__ rsum)
{
    if (blockIdx.x == 6240) {
        const int tid = threadIdx.x;
        if (tid < 576) {
            const int g = tid * 4;
            float4 f;
            if (g < 768) {
                f = *(const float4*)(bq + g);
                f.x *= SCALE_; f.y *= SCALE_; f.z *= SCALE_; f.w *= SCALE_;
            } else if (g < 1536) {
                f = *(const float4*)(bk + g - 768);
            } else {
                f = *(const float4*)(bv + g - 1536);
            }
            *(float4*)(bqkv + g) = f;
        }
        const float4 zz = make_float4(0.f, 0.f, 0.f, 0.f);
        #pragma unroll
        for (int k = 0; k < 16; ++k)
            *(float4*)(rsum + tid * 64 + k * 4) = zz;
        return;
    }
    const int i = blockIdx.x * blockDim.x + threadIdx.x;  // 0 .. 16640*96-1
    const int row = i / 96;
    const int c8  = (i - row * 96) * 8;
    const int b   = row / SM_;
    const int tt  = row - b * SM_;
    const float* src = (tt < S_) ? (x + ((size_t)b * S_ + tt) * D_ + c8)
                                 : (mem + (size_t)(tt - S_) * D_ + c8);
    const float4 f0 = *(const float4*)src;
    const float4 f1 = *(const float4*)(src + 4);
    bf16x8 v;
    v[0] = (bf16)f0.x; v[1] = (bf16)f0.y; v[2] = (bf16)f0.z; v[3] = (bf16)f0.w;
    v[4] = (bf16)f1.x; v[5] = (bf16)f1.y; v[6] = (bf16)f1.z; v[7] = (bf16)f1.w;
    *(bf16x8*)(cs + (size_t)row * D_ + c8) = v;
}

// ---------------------------------------------------------------------------
extern "C" void kernel_launch(void* const* d_in, const int* in_sizes, int n_in,
                              void* d_out, int out_size, void* d_ws, size_t ws_size,
                              hipStream_t stream) {
    const float* x    = (const float*)d_in[0];
    const float* mask = (const float*)d_in[1];
    const float* mem  = (const float*)d_in[2];
    const float* wq   = (const float*)d_in[3];
    const float* bq   = (const float*)d_in[4];
    const float* wk   = (const float*)d_in[5];
    const float* bk   = (const float*)d_in[6];
    const float* wv   = (const float*)d_in[7];
    const float* bv   = (const float*)d_in[8];
    const float* wo   = (const float*)d_in[9];
    const float* bo   = (const float*)d_in[10];

    bf16* w = (bf16*)d_ws;
    const size_t NW  = (size_t)D_ * D_;          //   589824
    const size_t NCS = (size_t)B_ * SM_ * D_;    // 12779520 (cstream / head_out)
    const size_t NQ  = (size_t)B_ * S_ * D_;     // 12582912
    const size_t NKV = (size_t)B_ * SM_ * D_;    // 12779520
    const size_t NVT = (size_t)B_ * D_ * SMP_;   // 13369344
    const size_t NEM = (size_t)S_ * SM_;         //  1064960
    bf16* wqkv = w;                // [2304][768] (wq pre-scaled)
    bf16* wob  = wqkv + 3 * NW;
    bf16* emb  = wob + NW;         // emask bf16 [1024][1040]
    bf16* cs   = emb + NEM;        // concat(x, mem) bf16; reused as head_out
    bf16* qb   = cs  + NCS;
    bf16* kb   = qb  + NQ;
    bf16* vtb  = kb  + NKV;
    bf16* Pb   = vtb + NVT;        // [B,1024,1088] unnormalized probs
    float* bqkv = (float*)(Pb + (size_t)B_ * S_ * SMP_);  // [2304] fp32
    float* rsum = bqkv + 2304;                            // [16384] fp32

    castw4_k<<<dim3(576, 4), 256, 0, stream>>>(wq, wk, wv, wo, wqkv, wob);
    emask_k<<<1040, 256, 0, stream>>>(mask, emb);
    castx_k<<<6241, 256, 0, stream>>>(x, mem, cs, bq, bk, bv, bqkv, rsum);

    // fused QKV: cs @ [wq*SC; wk; wv]^T + bqkv -> qb / kb / vtb(transposed)
    gemm_k<3, 3><<<dim3(18, 130), 256, 0, stream>>>(
        cs, wqkv, bqkv, qb, kb, vtb, D_, D_, 0, D_, 3 * D_, 0, 0, 0);

    // P_unnorm = exp(q @ k^T) * emask; per-row sums atomically -> rsum
    gemm_k<4, 1><<<1152, 256, 0, stream>>>(
        qb, kb, nullptr, Pb, rsum, emb, D_, D_, SMP_, D_, SM_,
        (long)S_ * D_, (long)SM_ * D_, (long)S_ * SMP_);

    // head_out = (P_unnorm @ V) / rsum  (XCD-swizzled) -> cs reused
    gemm_k<5, 2><<<768, 256, 0, stream>>>(
        Pb, vtb, rsum, cs, nullptr, nullptr, SMP_, SMP_, D_, SMP_, D_,
        (long)S_ * SMP_, (long)D_ * SMP_, (long)S_ * D_);

    // out = head_out @ wo^T + bo (fp32)
    gemm_k<1, 3><<<dim3(6, 128), 256, 0, stream>>>(
        cs, wob, bo, d_out, nullptr, nullptr, D_, D_, D_, D_, D_, 0, 0, 0);
}

// Round 5
// 350.153 us; speedup vs baseline: 1.0470x; 1.0470x over previous
//
#include <hip/hip_runtime.h>
#include <math.h>
#include <stdint.h>

#define D_    768
#define B_    16
#define S_    1024
#define M_    16
#define SM_   1040           // S + M
#define SMP_  1088           // padded kv length (17*64) for PV K-loop
#define SCALE_ 0.036084392f  // 1/sqrt(768)

typedef __bf16 bf16;
typedef __attribute__((ext_vector_type(8))) __bf16 bf16x8;
typedef __attribute__((ext_vector_type(4))) __bf16 bf16x4;
typedef __attribute__((ext_vector_type(4))) float  f32x4;

// async global->LDS, 16B per lane; LDS dest = wave-uniform base + lane*16
#define GL16(gp, lp) __builtin_amdgcn_global_load_lds( \
    (const __attribute__((address_space(1))) void*)(gp), \
    (__attribute__((address_space(3))) void*)(lp), 16, 0, 0)

// ---------------------------------------------------------------------------
// NT GEMM, 256x128 tile, BK=64, bf16 MFMA 16x16x32, 8 waves (4M x 2N),
// per-wave 64x64 output (acc 4x4) -- the same verified inner loop as the
// 128x128 m97 structure, retiled for arithmetic intensity.
// C[row, col] = sum_k A[row,k] * B[col,k]
//
// WHY 256x128: R1/R3 counters showed MfmaUtil pinned at 27-29% with nothing
// else saturated. Per-CU staging math: 128^2 tile = 32KB/step for 2.1 MFLOP
// (64 FLOP/B); at 3 blocks/CU the required L2 pull rate is ~35-39 TB/s =
// the measured L2 ceiling -> L2-BW-bound, predicted util 27% (matches).
// 256x128 stages 48KB/step for 4.2 MFLOP (87 FLOP/B); at 2 blocks/CU the
// required rate is ~28 TB/s < ceiling. Schedule unchanged (R2/R4 showed
// pipelining restructures lose; this is a bandwidth fix, not latency).
//
// LDS 48 KB single-buffered; 16B chunks XOR-swizzled within each 128B row
// (chunk p holds global chunk p^(row&7), pre-swizzled global source,
// linear LDS dest per gload_lds constraint). Bank-conflict-free (R1-R4: 0).
//
// GM: 1 = flat XCD-swizzled scores (4 row x 9 col x 16 z; xcd owns 2 batches)
//     2 = flat XCD-swizzled PV (4 x 6 x 16)
//     3 = m204-bijective XCD-chunked, col-fast within chunk (QKV / proj)
//
// OUTMODE 1: fp32 row-major + bias (aux).
// OUTMODE 3: fused QKV. B=[wq*SCALE; wk; wv] (2304 rows), wsel=col0/768,
//   bias=aux (bqkv, bq pre-scaled). Q->Cout[b,t<1024,:] bf16;
//   K->C2 [16640,768] bf16; V->C3 Vt[b,e,t] (ldc 1088) bf16x4.
// OUTMODE 4: probs epilogue. P = bf16(exp(acc) * emask[t,col]) for col<1040,
//   0 for pad cols [1040,1088); skip col>=1088. Per-row partial sums
//   wave-reduced and atomicAdd'ed into rsum (= C2, zero-initialized).
// OUTMODE 5: PV epilogue: out = bf16(acc / rsum[z*1024+row]) (rsum = aux).
// ---------------------------------------------------------------------------
template<int OUTMODE, int GM>
__launch_bounds__(512, 4)
__global__ void gemm_k(const bf16*  __restrict__ Am,
                       const bf16*  __restrict__ Bm,
                       const float* __restrict__ aux,
                       void* __restrict__ Cout,
                       void* __restrict__ C2,
                       void* __restrict__ C3,
                       int lda, int ldb, int ldc,
                       int K, int colsB,
                       long sA, long sB, long sC)
{
    __shared__ __attribute__((aligned(16))) bf16 As[256 * 64];
    __shared__ __attribute__((aligned(16))) bf16 Bs[128 * 64];

    const int t    = threadIdx.x;
    const int l    = t & 63;
    const int wv   = t >> 6;          // 0..7

    int row0, col0, z;
    if (GM == 1) {
        const int bid = blockIdx.x;           // 576 blocks
        const int xcd = bid & 7, s = bid >> 3;
        z = xcd * 2 + s / 36;
        const int r = s % 36;
        row0 = (r & 3) * 256; col0 = (r >> 2) * 128;
    } else if (GM == 2) {
        const int bid = blockIdx.x;           // 384 blocks
        const int xcd = bid & 7, s = bid >> 3;
        z = xcd * 2 + s / 24;
        const int r = s % 24;
        row0 = (r & 3) * 256; col0 = (r >> 2) * 128;
    } else {
        // m204 bijective XCD chunking: xcd = bid%8 owns a contiguous wg run
        const int gx  = gridDim.x;
        const int nwg = gx * gridDim.y;
        const int bid = blockIdx.y * gx + blockIdx.x;
        const int qn  = nwg >> 3, rr = nwg & 7;
        const int xcd = bid & 7,  idx = bid >> 3;
        const int wg  = (xcd < rr ? xcd * (qn + 1)
                                  : rr * (qn + 1) + (xcd - rr) * qn) + idx;
        row0 = (wg / gx) * 256; col0 = (wg % gx) * 128; z = 0;
    }

    // staging: A = 256 rows (4 GL16/wave, 32 rows each), B = 128 rows (2)
    const bf16* agb[4];
    const bf16* bgb[2];
    #pragma unroll
    for (int i = 0; i < 4; ++i) {
        const int r = wv * 32 + i * 8 + (l >> 3);    // tile row 0..255
        const int c = (l & 7) ^ (r & 7);             // swizzled source chunk
        agb[i] = Am + (size_t)z * sA + (size_t)(row0 + r) * lda + c * 8;
    }
    #pragma unroll
    for (int q = 0; q < 2; ++q) {
        const int r = wv * 16 + q * 8 + (l >> 3);    // tile row 0..127
        const int c = (l & 7) ^ (r & 7);
        int bcol = col0 + r;
        if (bcol > colsB - 1) bcol = colsB - 1;
        bgb[q] = Bm + (size_t)z * sB + (size_t)bcol * ldb + c * 8;
    }

    f32x4 acc[4][4];
    #pragma unroll
    for (int i = 0; i < 4; ++i)
        #pragma unroll
        for (int j = 0; j < 4; ++j)
            acc[i][j] = (f32x4){0.f, 0.f, 0.f, 0.f};

    const int wr0 = (wv & 3) * 64;     // 4 waves in M
    const int wc0 = (wv >> 2) * 64;    // 2 waves in N
    const int lq  = l >> 4;
    const int lm  = l & 15;

    for (int kt = 0; kt < K; kt += 64) {
        __syncthreads();   // previous tile's fragment reads done
        #pragma unroll
        for (int i = 0; i < 4; ++i)
            GL16(agb[i] + kt, &As[(wv * 4 + i) * 512]);
        #pragma unroll
        for (int q = 0; q < 2; ++q)
            GL16(bgb[q] + kt, &Bs[(wv * 2 + q) * 512]);
        __syncthreads();   // staging visible

        #pragma unroll
        for (int ks = 0; ks < 2; ++ks) {
            bf16x8 af[4], bfr[4];
            #pragma unroll
            for (int i = 0; i < 4; ++i) {
                const int rowA = wr0 + i * 16 + lm;
                const int p = (ks * 4 + lq) ^ (rowA & 7);
                af[i] = *(const bf16x8*)&As[rowA * 64 + p * 8];
            }
            #pragma unroll
            for (int j = 0; j < 4; ++j) {
                const int rowB = wc0 + j * 16 + lm;
                const int p = (ks * 4 + lq) ^ (rowB & 7);
                bfr[j] = *(const bf16x8*)&Bs[rowB * 64 + p * 8];
            }
            #pragma unroll
            for (int i = 0; i < 4; ++i)
                #pragma unroll
                for (int j = 0; j < 4; ++j)
                    acc[i][j] = __builtin_amdgcn_mfma_f32_16x16x32_bf16(
                        af[i], bfr[j], acc[i][j], 0, 0, 0);
        }
    }

    // epilogue: C/D layout col=lane&15, row=quad*4+reg (m89/m91 verified)
    if (OUTMODE == 4) {
        // probs + fused row-sum atomics
        const bf16* em = (const bf16*)C3;
        float* rsum = (float*)C2;
        #pragma unroll
        for (int i = 0; i < 4; ++i) {
            const int t0 = row0 + wr0 + i * 16 + lq * 4;
            #pragma unroll
            for (int r = 0; r < 4; ++r) {
                float part = 0.f;
                #pragma unroll
                for (int j = 0; j < 4; ++j) {
                    const int gcol = col0 + wc0 + j * 16 + lm;
                    float val = 0.f;
                    if (gcol < SM_)
                        val = __expf(acc[i][j][r])
                            * (float)em[(size_t)(t0 + r) * SM_ + gcol];
                    const bf16 vb = (bf16)val;
                    part += (float)vb;
                    if (gcol < SMP_)
                        ((bf16*)Cout)[(size_t)z * sC
                            + (size_t)(t0 + r) * ldc + gcol] = vb;
                }
                // reduce over the 16 lm lanes (lane bits 0..3)
                #pragma unroll
                for (int o = 8; o; o >>= 1) part += __shfl_xor(part, o);
                if (lm == 0)
                    atomicAdd(&rsum[z * S_ + t0 + r], part);
            }
        }
        return;
    }

    float rin[4][4];
    if (OUTMODE == 5) {
        #pragma unroll
        for (int i = 0; i < 4; ++i) {
            const int t0 = row0 + wr0 + i * 16 + lq * 4;
            #pragma unroll
            for (int r = 0; r < 4; ++r)
                rin[i][r] = 1.f / aux[z * S_ + t0 + r];
        }
    }

    const int wsel = (OUTMODE == 3) ? (col0 / 768) : 0;
    #pragma unroll
    for (int j = 0; j < 4; ++j) {
        const int gcol = col0 + wc0 + j * 16 + lm;
        #pragma unroll
        for (int i = 0; i < 4; ++i) {
            const int t0 = row0 + wr0 + i * 16 + lq * 4;  // 4-aligned
            if (OUTMODE == 3) {
                const int lcol = gcol - wsel * 768;
                const float bv = aux[gcol];
                const int b  = t0 / SM_;
                const int tt = t0 - b * SM_;
                if (wsel == 0) {             // Q -> [B,1024,768] bf16
                    if (tt < S_) {
                        #pragma unroll
                        for (int r = 0; r < 4; ++r)
                            ((bf16*)Cout)[((size_t)b * S_ + tt + r) * D_ + lcol]
                                = (bf16)(acc[i][j][r] + bv);
                    }
                } else if (wsel == 1) {      // K -> [16640,768] bf16
                    #pragma unroll
                    for (int r = 0; r < 4; ++r)
                        ((bf16*)C2)[(size_t)(t0 + r) * D_ + lcol]
                            = (bf16)(acc[i][j][r] + bv);
                } else {                     // V -> Vt[b, e, t] bf16x4
                    bf16x4 o;
                    #pragma unroll
                    for (int r = 0; r < 4; ++r) o[r] = (bf16)(acc[i][j][r] + bv);
                    *(bf16x4*)((bf16*)C3 +
                        ((size_t)b * D_ + lcol) * SMP_ + tt) = o;
                }
            } else if (OUTMODE == 5) {       // PV, normalize by row sum
                #pragma unroll
                for (int r = 0; r < 4; ++r)
                    ((bf16*)Cout)[(size_t)z * sC + (size_t)(t0 + r) * ldc + gcol]
                        = (bf16)(acc[i][j][r] * rin[i][r]);
            } else {                         // OUTMODE 1: fp32 + bias
                if (gcol < colsB) {
                    const float bv = aux ? aux[gcol] : 0.f;
                    #pragma unroll
                    for (int r = 0; r < 4; ++r)
                        ((float*)Cout)[(size_t)z * sC
                            + (size_t)(t0 + r) * ldc + gcol]
                            = acc[i][j][r] + bv;
                }
            }
        }
    }
}

// ---------------------------------------------------------------------------
// Weight cast: [wq*SCALE; wk; wv] -> wqkv [2304,768] bf16, wo -> wob
// ---------------------------------------------------------------------------
__global__ void castw4_k(const float* __restrict__ w0, const float* __restrict__ w1,
                         const float* __restrict__ w2, const float* __restrict__ w3,
                         bf16* __restrict__ wqkv, bf16* __restrict__ wob)
{
    const float* in;
    bf16* out;
    float sc = 1.f;
    const size_t NW = (size_t)D_ * D_;
    switch (blockIdx.y) {
        case 0: in = w0; out = wqkv;          sc = SCALE_; break;
        case 1: in = w1; out = wqkv + NW;     break;
        case 2: in = w2; out = wqkv + 2 * NW; break;
        default: in = w3; out = wob;          break;
    }
    const int i = blockIdx.x * blockDim.x + threadIdx.x;   // float4 chunks
    const float4 f = ((const float4*)in)[i];
    bf16x4 v;
    v[0] = (bf16)(f.x * sc); v[1] = (bf16)(f.y * sc);
    v[2] = (bf16)(f.z * sc); v[3] = (bf16)(f.w * sc);
    ((bf16x4*)out)[i] = v;
}

// ---------------------------------------------------------------------------
// emask[t, col] = bf16(exp(mask[t, col]))   (1024 x 1040)
// ---------------------------------------------------------------------------
__global__ void emask_k(const float* __restrict__ mask, bf16* __restrict__ em)
{
    const int i = blockIdx.x * blockDim.x + threadIdx.x;  // float4 chunks
    const float4 f = ((const float4*)mask)[i];
    bf16x4 v;
    v[0] = (bf16)__expf(f.x); v[1] = (bf16)__expf(f.y);
    v[2] = (bf16)__expf(f.z); v[3] = (bf16)__expf(f.w);
    ((bf16x4*)em)[i] = v;
}

// ---------------------------------------------------------------------------
// cstream[b*1040 + t][e] = bf16( t<1024 ? x[b,t,e] : mem[t-1024,e] )
// Block 6240: concat bq*SCALE|bk|bv into bqkv [2304] and zero rsum [16384].
// ---------------------------------------------------------------------------
__global__ void castx_k(const float* __restrict__ x, const float* __restrict__ mem,
                        bf16* __restrict__ cs,
                        const float* __restrict__ bq, const float* __restrict__ bk,
                        const float* __restrict__ bv, float* __restrict__ bqkv,
                        float* __restrict__ rsum)
{
    if (blockIdx.x == 6240) {
        const int tid = threadIdx.x;
        if (tid < 576) {
            const int g = tid * 4;
            float4 f;
            if (g < 768) {
                f = *(const float4*)(bq + g);
                f.x *= SCALE_; f.y *= SCALE_; f.z *= SCALE_; f.w *= SCALE_;
            } else if (g < 1536) {
                f = *(const float4*)(bk + g - 768);
            } else {
                f = *(const float4*)(bv + g - 1536);
            }
            *(float4*)(bqkv + g) = f;
        }
        const float4 zz = make_float4(0.f, 0.f, 0.f, 0.f);
        #pragma unroll
        for (int k = 0; k < 16; ++k)
            *(float4*)(rsum + tid * 64 + k * 4) = zz;
        return;
    }
    const int i = blockIdx.x * blockDim.x + threadIdx.x;  // 0 .. 16640*96-1
    const int row = i / 96;
    const int c8  = (i - row * 96) * 8;
    const int b   = row / SM_;
    const int tt  = row - b * SM_;
    const float* src = (tt < S_) ? (x + ((size_t)b * S_ + tt) * D_ + c8)
                                 : (mem + (size_t)(tt - S_) * D_ + c8);
    const float4 f0 = *(const float4*)src;
    const float4 f1 = *(const float4*)(src + 4);
    bf16x8 v;
    v[0] = (bf16)f0.x; v[1] = (bf16)f0.y; v[2] = (bf16)f0.z; v[3] = (bf16)f0.w;
    v[4] = (bf16)f1.x; v[5] = (bf16)f1.y; v[6] = (bf16)f1.z; v[7] = (bf16)f1.w;
    *(bf16x8*)(cs + (size_t)row * D_ + c8) = v;
}

// ---------------------------------------------------------------------------
extern "C" void kernel_launch(void* const* d_in, const int* in_sizes, int n_in,
                              void* d_out, int out_size, void* d_ws, size_t ws_size,
                              hipStream_t stream) {
    const float* x    = (const float*)d_in[0];
    const float* mask = (const float*)d_in[1];
    const float* mem  = (const float*)d_in[2];
    const float* wq   = (const float*)d_in[3];
    const float* bq   = (const float*)d_in[4];
    const float* wk   = (const float*)d_in[5];
    const float* bk   = (const float*)d_in[6];
    const float* wv   = (const float*)d_in[7];
    const float* bv   = (const float*)d_in[8];
    const float* wo   = (const float*)d_in[9];
    const float* bo   = (const float*)d_in[10];

    bf16* w = (bf16*)d_ws;
    const size_t NW  = (size_t)D_ * D_;          //   589824
    const size_t NCS = (size_t)B_ * SM_ * D_;    // 12779520 (cstream / head_out)
    const size_t NQ  = (size_t)B_ * S_ * D_;     // 12582912
    const size_t NKV = (size_t)B_ * SM_ * D_;    // 12779520
    const size_t NVT = (size_t)B_ * D_ * SMP_;   // 13369344
    const size_t NEM = (size_t)S_ * SM_;         //  1064960
    bf16* wqkv = w;                // [2304][768] (wq pre-scaled)
    bf16* wob  = wqkv + 3 * NW;
    bf16* emb  = wob + NW;         // emask bf16 [1024][1040]
    bf16* cs   = emb + NEM;        // concat(x, mem) bf16; reused as head_out
    bf16* qb   = cs  + NCS;
    bf16* kb   = qb  + NQ;
    bf16* vtb  = kb  + NKV;
    bf16* Pb   = vtb + NVT;        // [B,1024,1088] unnormalized probs
    float* bqkv = (float*)(Pb + (size_t)B_ * S_ * SMP_);  // [2304] fp32
    float* rsum = bqkv + 2304;                            // [16384] fp32

    castw4_k<<<dim3(576, 4), 256, 0, stream>>>(wq, wk, wv, wo, wqkv, wob);
    emask_k<<<1040, 256, 0, stream>>>(mask, emb);
    castx_k<<<6241, 256, 0, stream>>>(x, mem, cs, bq, bk, bv, bqkv, rsum);

    // fused QKV: cs @ [wq*SC; wk; wv]^T + bqkv -> qb / kb / vtb(transposed)
    gemm_k<3, 3><<<dim3(18, 65), 512, 0, stream>>>(
        cs, wqkv, bqkv, qb, kb, vtb, D_, D_, 0, D_, 3 * D_, 0, 0, 0);

    // P_unnorm = exp(q @ k^T) * emask; per-row sums atomically -> rsum
    gemm_k<4, 1><<<576, 512, 0, stream>>>(
        qb, kb, nullptr, Pb, rsum, emb, D_, D_, SMP_, D_, SM_,
        (long)S_ * D_, (long)SM_ * D_, (long)S_ * SMP_);

    // head_out = (P_unnorm @ V) / rsum  (XCD-swizzled) -> cs reused
    gemm_k<5, 2><<<384, 512, 0, stream>>>(
        Pb, vtb, rsum, cs, nullptr, nullptr, SMP_, SMP_, D_, SMP_, D_,
        (long)S_ * SMP_, (long)D_ * SMP_, (long)S_ * D_);

    // out = head_out @ wo^T + bo (fp32)
    gemm_k<1, 3><<<dim3(6, 64), 512, 0, stream>>>(
        cs, wob, bo, d_out, nullptr, nullptr, D_, D_, D_, D_, D_, 0, 0, 0);
}

// Round 6
// 315.359 us; speedup vs baseline: 1.1625x; 1.1103x over previous
//
#include <hip/hip_runtime.h>
#include <math.h>
#include <stdint.h>

#define D_    768
#define B_    16
#define S_    1024
#define M_    16
#define SM_   1040           // S + M
#define SMP_  1088           // padded kv length (17*64) for PV K-loop
#define SCALE_ 0.036084392f  // 1/sqrt(768)

typedef __bf16 bf16;
typedef __attribute__((ext_vector_type(8))) __bf16 bf16x8;
typedef __attribute__((ext_vector_type(4))) __bf16 bf16x4;
typedef __attribute__((ext_vector_type(4))) float  f32x4;

// async global->LDS, 16B per lane; LDS dest = wave-uniform base + lane*16
#define GL16(gp, lp) __builtin_amdgcn_global_load_lds( \
    (const __attribute__((address_space(1))) void*)(gp), \
    (__attribute__((address_space(3))) void*)(lp), 16, 0, 0)

// ---------------------------------------------------------------------------
// NT GEMM, 128x128 tile, BK=64, bf16 MFMA 16x16x32, 4 waves (2x2), 4x4 frags.
// C[row, col] = sum_k A[row,k] * B[col,k]
// K-loop identical to the verified 338us R3 kernel (global_load_lds width=16,
// XOR-swizzled 16B chunks, 2-barrier steps, 3 blocks/CU).
//
// EPILOGUES REWORKED (R5 diagnosis): the old epilogues issued 64 scattered
// 2B global stores per thread (column-strided through the C/D layout) and,
// for scores, 64 scattered 2B emask gathers -- measured as WRITE_SIZE
// amplification (115MB vs 76 logical on QKV) and ~15-30% of block time.
// Now: per-wave LDS bounce through the dead As/Bs space (one Ls array):
// 2B swizzled LDS writes -> barrier -> b128 row reads -> 16B coalesced
// global stores. V uses a transposed bounce; scores stages the em tile
// into Ls via GL16 and computes P in place, then writes back 16B chunks.
// Numerics bit-identical to R3.
//
// GM: 1 = flat XCD-swizzled scores (8 row x 9 col x 16 z; xcd owns 2 batches)
//     2 = flat XCD-swizzled PV (8 x 6 x 16)
//     3 = m204-bijective XCD-chunked, col-fast within chunk (QKV / proj)
//
// OUTMODE 1: fp32 row-major + bias (aux)  [unchanged: stores already 64B/line]
// OUTMODE 3: fused QKV. B=[wq*SCALE; wk; wv], wsel=col0/768, bias=aux.
//   Q->Cout[b,t<1024,:] bf16; K->C2 [16640,768] bf16; V->C3 Vt[b,e,t] bf16.
// OUTMODE 4: probs epilogue. P = bf16(exp(acc)*em) for col<1040, 0 for pad
//   cols [1040,1088), skip col>=1088; per-row sums -> atomicAdd rsum (=C2).
// OUTMODE 5: PV epilogue: out = bf16(acc / rsum[z*1024+row]) (rsum = aux).
// ---------------------------------------------------------------------------
template<int OUTMODE, int GM>
__launch_bounds__(256, 3)
__global__ void gemm_k(const bf16*  __restrict__ Am,
                       const bf16*  __restrict__ Bm,
                       const float* __restrict__ aux,
                       void* __restrict__ Cout,
                       void* __restrict__ C2,
                       void* __restrict__ C3,
                       int lda, int ldb, int ldc,
                       int K, int colsB,
                       long sA, long sB, long sC)
{
    __shared__ __attribute__((aligned(16))) bf16 Ls[16384];  // 32KB
    bf16* As = Ls;            // [128][64] during K-loop
    bf16* Bs = Ls + 8192;

    const int t    = threadIdx.x;
    const int l    = t & 63;
    const int wv   = t >> 6;

    int row0, col0, z;
    if (GM == 1) {
        const int bid = blockIdx.x;           // 1152 blocks
        const int xcd = bid & 7, s = bid >> 3;
        z = xcd * 2 + s / 72;
        const int r = s % 72;
        row0 = (r & 7) * 128; col0 = (r >> 3) * 128;
    } else if (GM == 2) {
        const int bid = blockIdx.x;           // 768 blocks
        const int xcd = bid & 7, s = bid >> 3;
        z = xcd * 2 + s / 48;
        const int r = s % 48;
        row0 = (r & 7) * 128; col0 = (r >> 3) * 128;
    } else {
        // m204 bijective XCD chunking: xcd = bid%8 owns a contiguous wg run
        const int gx  = gridDim.x;
        const int nwg = gx * gridDim.y;
        const int bid = blockIdx.y * gx + blockIdx.x;
        const int qn  = nwg >> 3, rr = nwg & 7;
        const int xcd = bid & 7,  idx = bid >> 3;
        const int wg  = (xcd < rr ? xcd * (qn + 1)
                                  : rr * (qn + 1) + (xcd - rr) * qn) + idx;
        row0 = (wg / gx) * 128; col0 = (wg % gx) * 128; z = 0;
    }

    const bf16* agb[4];
    const bf16* bgb[4];
    #pragma unroll
    for (int i = 0; i < 4; ++i) {
        const int r = (wv * 4 + i) * 8 + (l >> 3);   // tile row 0..127
        const int c = (l & 7) ^ (r & 7);             // swizzled source chunk
        agb[i] = Am + (size_t)z * sA + (size_t)(row0 + r) * lda + c * 8;
        int bcol = col0 + r;
        if (bcol > colsB - 1) bcol = colsB - 1;
        bgb[i] = Bm + (size_t)z * sB + (size_t)bcol * ldb + c * 8;
    }

    f32x4 acc[4][4];
    #pragma unroll
    for (int i = 0; i < 4; ++i)
        #pragma unroll
        for (int j = 0; j < 4; ++j)
            acc[i][j] = (f32x4){0.f, 0.f, 0.f, 0.f};

    const int wr0 = (wv & 1) * 64;
    const int wc0 = (wv >> 1) * 64;
    const int lq  = l >> 4;
    const int lm  = l & 15;

    for (int kt = 0; kt < K; kt += 64) {
        __syncthreads();   // previous tile's fragment reads done
        #pragma unroll
        for (int i = 0; i < 4; ++i)
            GL16(agb[i] + kt, &As[(wv * 4 + i) * 512]);
        #pragma unroll
        for (int i = 0; i < 4; ++i)
            GL16(bgb[i] + kt, &Bs[(wv * 4 + i) * 512]);
        __syncthreads();   // staging visible

        #pragma unroll
        for (int ks = 0; ks < 2; ++ks) {
            bf16x8 af[4], bfr[4];
            #pragma unroll
            for (int i = 0; i < 4; ++i) {
                const int rowA = wr0 + i * 16 + lm;
                const int p = (ks * 4 + lq) ^ (rowA & 7);
                af[i] = *(const bf16x8*)&As[rowA * 64 + p * 8];
            }
            #pragma unroll
            for (int j = 0; j < 4; ++j) {
                const int rowB = wc0 + j * 16 + lm;
                const int p = (ks * 4 + lq) ^ (rowB & 7);
                bfr[j] = *(const bf16x8*)&Bs[rowB * 64 + p * 8];
            }
            #pragma unroll
            for (int i = 0; i < 4; ++i)
                #pragma unroll
                for (int j = 0; j < 4; ++j)
                    acc[i][j] = __builtin_amdgcn_mfma_f32_16x16x32_bf16(
                        af[i], bfr[j], acc[i][j], 0, 0, 0);
        }
    }

    __syncthreads();   // all waves done reading As/Bs; LDS reusable

    // epilogue: C/D layout col=lane&15, row=quad*4+reg (m89/m91 verified)
    if (OUTMODE == 4) {
        // ---- stage em tile [128 rows][128 cols] (256B rows) into Ls ----
        const int lr = l >> 4;            // row within 4-row GL16 group
        const int pc = l & 15;            // phys 16B chunk 0..15
        #pragma unroll
        for (int g = 0; g < 8; ++g) {
            const int row = wv * 32 + g * 4 + lr;          // 0..127
            const int sc  = pc ^ ((row & 7) << 1);         // source chunk
            int gc = col0 + sc * 8;
            if (gc > 1032) gc = 1032;                      // clamp (tile 8)
            GL16((const bf16*)C3 + (size_t)(row0 + row) * SM_ + gc,
                 &Ls[(wv * 32 + g * 4) * 128]);
        }
        asm volatile("s_waitcnt vmcnt(0)" ::: "memory");
        __syncthreads();
        // ---- compute P in place; accumulate row sums ----
        float* rsum = (float*)C2;
        #pragma unroll
        for (int i = 0; i < 4; ++i) {
            #pragma unroll
            for (int r = 0; r < 4; ++r) {
                const int row = wr0 + i * 16 + lq * 4 + r;   // block-local q
                float part = 0.f;
                #pragma unroll
                for (int j = 0; j < 4; ++j) {
                    const int col  = wc0 + j * 16 + lm;
                    const int gcol = col0 + col;
                    const int idx  = row * 128
                        + (((col >> 3) ^ ((row & 7) << 1)) * 8) + (col & 7);
                    float val = 0.f;
                    if (gcol < SM_)
                        val = __expf(acc[i][j][r]) * (float)Ls[idx];
                    const bf16 vb = (bf16)val;
                    part += (float)vb;
                    Ls[idx] = vb;          // in-place: same thread, same slot
                }
                #pragma unroll
                for (int o = 8; o; o >>= 1) part += __shfl_xor(part, o);
                if (lm == 0)
                    atomicAdd(&rsum[z * S_ + row0 + row], part);
            }
        }
        __syncthreads();
        // ---- coalesced 16B write-back ----
        #pragma unroll
        for (int c = 0; c < 8; ++c) {
            const int row = wv * 32 + c * 4 + lr;
            bf16x8 v = *(const bf16x8*)&Ls[row * 128 + pc * 8];
            const int gcol = col0 + (pc ^ ((row & 7) << 1)) * 8;
            if (gcol < SMP_)
                *(bf16x8*)((bf16*)Cout + (size_t)z * sC
                           + (size_t)(row0 + row) * ldc + gcol) = v;
        }
        return;
    }

    bf16* W = Ls + wv * 4096;      // per-wave 8KB bounce tile [64][64]

    if (OUTMODE == 5) {            // PV, normalize by row sum
        float rin[4][4];
        #pragma unroll
        for (int i = 0; i < 4; ++i) {
            const int t0 = row0 + wr0 + i * 16 + lq * 4;
            #pragma unroll
            for (int r = 0; r < 4; ++r)
                rin[i][r] = 1.f / aux[z * S_ + t0 + r];
        }
        #pragma unroll
        for (int i = 0; i < 4; ++i)
            #pragma unroll
            for (int j = 0; j < 4; ++j)
                #pragma unroll
                for (int r = 0; r < 4; ++r) {
                    const int row = i * 16 + lq * 4 + r;   // local
                    const int col = j * 16 + lm;
                    W[row * 64 + (((col >> 3) ^ (row & 7)) * 8) + (col & 7)]
                        = (bf16)(acc[i][j][r] * rin[i][r]);
                }
        __syncthreads();
        #pragma unroll
        for (int c = 0; c < 8; ++c) {
            const int row = c * 8 + (l >> 3);
            const int q8  = l & 7;
            bf16x8 v = *(const bf16x8*)&W[row * 64 + q8 * 8];
            const int gcol = col0 + wc0 + (q8 ^ (row & 7)) * 8;
            const int grow = row0 + wr0 + row;
            *(bf16x8*)((bf16*)Cout + (size_t)z * sC
                       + (size_t)grow * ldc + gcol) = v;
        }
        return;
    }

    if (OUTMODE == 3) {
        const int wsel = col0 / 768;
        const int colb = col0 + wc0;
        if (wsel < 2) {                     // Q / K: row-major bounce
            #pragma unroll
            for (int i = 0; i < 4; ++i)
                #pragma unroll
                for (int j = 0; j < 4; ++j) {
                    const float bv = aux[colb + j * 16 + lm];
                    #pragma unroll
                    for (int r = 0; r < 4; ++r) {
                        const int row = i * 16 + lq * 4 + r;
                        const int col = j * 16 + lm;
                        W[row * 64 + (((col >> 3) ^ (row & 7)) * 8) + (col & 7)]
                            = (bf16)(acc[i][j][r] + bv);
                    }
                }
            __syncthreads();
            #pragma unroll
            for (int c = 0; c < 8; ++c) {
                const int row = c * 8 + (l >> 3);
                const int q8  = l & 7;
                bf16x8 v = *(const bf16x8*)&W[row * 64 + q8 * 8];
                const int lcol = colb - wsel * 768 + (q8 ^ (row & 7)) * 8;
                const int grow = row0 + wr0 + row;
                if (wsel == 0) {            // Q -> [B,1024,768]
                    const int b  = grow / SM_;
                    const int tt = grow - b * SM_;
                    if (tt < S_)
                        *(bf16x8*)((bf16*)Cout
                            + ((size_t)b * S_ + tt) * D_ + lcol) = v;
                } else {                    // K -> [16640,768]
                    *(bf16x8*)((bf16*)C2 + (size_t)grow * D_ + lcol) = v;
                }
            }
        } else {                            // V: transposed bounce T[e][t]
            #pragma unroll
            for (int i = 0; i < 4; ++i)
                #pragma unroll
                for (int j = 0; j < 4; ++j) {
                    const float bv = aux[colb + j * 16 + lm];
                    #pragma unroll
                    for (int r = 0; r < 4; ++r) {
                        const int trow = i * 16 + lq * 4 + r;  // t-local
                        const int e    = j * 16 + lm;          // e-local
                        W[e * 64 + (((trow >> 3) ^ (e & 7)) * 8) + (trow & 7)]
                            = (bf16)(acc[i][j][r] + bv);
                    }
                }
            __syncthreads();
            #pragma unroll
            for (int c = 0; c < 8; ++c) {
                const int e  = c * 8 + (l >> 3);
                const int q8 = l & 7;
                bf16x8 v = *(const bf16x8*)&W[e * 64 + q8 * 8];
                const int tl   = (q8 ^ (e & 7)) * 8;       // t-local base
                const int grow = row0 + wr0 + tl;          // concat row
                const int b    = grow / SM_;               // 8|1040: no cross
                const int tt   = grow - b * SM_;
                const int eg   = colb - 1536 + e;
                *(bf16x8*)((bf16*)C3
                    + ((size_t)b * D_ + eg) * SMP_ + tt) = v;
            }
        }
        return;
    }

    // OUTMODE 1: fp32 + bias (stores are already full-line across lanes)
    #pragma unroll
    for (int j = 0; j < 4; ++j) {
        const int gcol = col0 + wc0 + j * 16 + lm;
        #pragma unroll
        for (int i = 0; i < 4; ++i) {
            const int t0 = row0 + wr0 + i * 16 + lq * 4;
            if (gcol < colsB) {
                const float bv = aux ? aux[gcol] : 0.f;
                #pragma unroll
                for (int r = 0; r < 4; ++r)
                    ((float*)Cout)[(size_t)z * sC
                        + (size_t)(t0 + r) * ldc + gcol]
                        = acc[i][j][r] + bv;
            }
        }
    }
}

// ---------------------------------------------------------------------------
// Weight cast: [wq*SCALE; wk; wv] -> wqkv [2304,768] bf16, wo -> wob
// ---------------------------------------------------------------------------
__global__ void castw4_k(const float* __restrict__ w0, const float* __restrict__ w1,
                         const float* __restrict__ w2, const float* __restrict__ w3,
                         bf16* __restrict__ wqkv, bf16* __restrict__ wob)
{
    const float* in;
    bf16* out;
    float sc = 1.f;
    const size_t NW = (size_t)D_ * D_;
    switch (blockIdx.y) {
        case 0: in = w0; out = wqkv;          sc = SCALE_; break;
        case 1: in = w1; out = wqkv + NW;     break;
        case 2: in = w2; out = wqkv + 2 * NW; break;
        default: in = w3; out = wob;          break;
    }
    const int i = blockIdx.x * blockDim.x + threadIdx.x;   // float4 chunks
    const float4 f = ((const float4*)in)[i];
    bf16x4 v;
    v[0] = (bf16)(f.x * sc); v[1] = (bf16)(f.y * sc);
    v[2] = (bf16)(f.z * sc); v[3] = (bf16)(f.w * sc);
    ((bf16x4*)out)[i] = v;
}

// ---------------------------------------------------------------------------
// emask[t, col] = bf16(exp(mask[t, col]))   (1024 x 1040)
// ---------------------------------------------------------------------------
__global__ void emask_k(const float* __restrict__ mask, bf16* __restrict__ em)
{
    const int i = blockIdx.x * blockDim.x + threadIdx.x;  // float4 chunks
    const float4 f = ((const float4*)mask)[i];
    bf16x4 v;
    v[0] = (bf16)__expf(f.x); v[1] = (bf16)__expf(f.y);
    v[2] = (bf16)__expf(f.z); v[3] = (bf16)__expf(f.w);
    ((bf16x4*)em)[i] = v;
}

// ---------------------------------------------------------------------------
// cstream[b*1040 + t][e] = bf16( t<1024 ? x[b,t,e] : mem[t-1024,e] )
// Block 6240: concat bq*SCALE|bk|bv into bqkv [2304] and zero rsum [16384].
// ---------------------------------------------------------------------------
__global__ void castx_k(const float* __restrict__ x, const float* __restrict__ mem,
                        bf16* __restrict__ cs,
                        const float* __restrict__ bq, const float* __restrict__ bk,
                        const float* __restrict__ bv, float* __restrict__ bqkv,
                        float* __restrict__ rsum)
{
    if (blockIdx.x == 6240) {
        const int tid = threadIdx.x;
        if (tid < 576) {
            const int g = tid * 4;
            float4 f;
            if (g < 768) {
                f = *(const float4*)(bq + g);
                f.x *= SCALE_; f.y *= SCALE_; f.z *= SCALE_; f.w *= SCALE_;
            } else if (g < 1536) {
                f = *(const float4*)(bk + g - 768);
            } else {
                f = *(const float4*)(bv + g - 1536);
            }
            *(float4*)(bqkv + g) = f;
        }
        const float4 zz = make_float4(0.f, 0.f, 0.f, 0.f);
        #pragma unroll
        for (int k = 0; k < 16; ++k)
            *(float4*)(rsum + tid * 64 + k * 4) = zz;
        return;
    }
    const int i = blockIdx.x * blockDim.x + threadIdx.x;  // 0 .. 16640*96-1
    const int row = i / 96;
    const int c8  = (i - row * 96) * 8;
    const int b   = row / SM_;
    const int tt  = row - b * SM_;
    const float* src = (tt < S_) ? (x + ((size_t)b * S_ + tt) * D_ + c8)
                                 : (mem + (size_t)(tt - S_) * D_ + c8);
    const float4 f0 = *(const float4*)src;
    const float4 f1 = *(const float4*)(src + 4);
    bf16x8 v;
    v[0] = (bf16)f0.x; v[1] = (bf16)f0.y; v[2] = (bf16)f0.z; v[3] = (bf16)f0.w;
    v[4] = (bf16)f1.x; v[5] = (bf16)f1.y; v[6] = (bf16)f1.z; v[7] = (bf16)f1.w;
    *(bf16x8*)(cs + (size_t)row * D_ + c8) = v;
}

// ---------------------------------------------------------------------------
extern "C" void kernel_launch(void* const* d_in, const int* in_sizes, int n_in,
                              void* d_out, int out_size, void* d_ws, size_t ws_size,
                              hipStream_t stream) {
    const float* x    = (const float*)d_in[0];
    const float* mask = (const float*)d_in[1];
    const float* mem  = (const float*)d_in[2];
    const float* wq   = (const float*)d_in[3];
    const float* bq   = (const float*)d_in[4];
    const float* wk   = (const float*)d_in[5];
    const float* bk   = (const float*)d_in[6];
    const float* wv   = (const float*)d_in[7];
    const float* bv   = (const float*)d_in[8];
    const float* wo   = (const float*)d_in[9];
    const float* bo   = (const float*)d_in[10];

    bf16* w = (bf16*)d_ws;
    const size_t NW  = (size_t)D_ * D_;          //   589824
    const size_t NCS = (size_t)B_ * SM_ * D_;    // 12779520 (cstream / head_out)
    const size_t NQ  = (size_t)B_ * S_ * D_;     // 12582912
    const size_t NKV = (size_t)B_ * SM_ * D_;    // 12779520
    const size_t NVT = (size_t)B_ * D_ * SMP_;   // 13369344
    const size_t NEM = (size_t)S_ * SM_;         //  1064960
    bf16* wqkv = w;                // [2304][768] (wq pre-scaled)
    bf16* wob  = wqkv + 3 * NW;
    bf16* emb  = wob + NW;         // emask bf16 [1024][1040]
    bf16* cs   = emb + NEM;        // concat(x, mem) bf16; reused as head_out
    bf16* qb   = cs  + NCS;
    bf16* kb   = qb  + NQ;
    bf16* vtb  = kb  + NKV;
    bf16* Pb   = vtb + NVT;        // [B,1024,1088] unnormalized probs
    float* bqkv = (float*)(Pb + (size_t)B_ * S_ * SMP_);  // [2304] fp32
    float* rsum = bqkv + 2304;                            // [16384] fp32

    castw4_k<<<dim3(576, 4), 256, 0, stream>>>(wq, wk, wv, wo, wqkv, wob);
    emask_k<<<1040, 256, 0, stream>>>(mask, emb);
    castx_k<<<6241, 256, 0, stream>>>(x, mem, cs, bq, bk, bv, bqkv, rsum);

    // fused QKV: cs @ [wq*SC; wk; wv]^T + bqkv -> qb / kb / vtb(transposed)
    gemm_k<3, 3><<<dim3(18, 130), 256, 0, stream>>>(
        cs, wqkv, bqkv, qb, kb, vtb, D_, D_, 0, D_, 3 * D_, 0, 0, 0);

    // P_unnorm = exp(q @ k^T) * emask; per-row sums atomically -> rsum
    gemm_k<4, 1><<<1152, 256, 0, stream>>>(
        qb, kb, nullptr, Pb, rsum, emb, D_, D_, SMP_, D_, SM_,
        (long)S_ * D_, (long)SM_ * D_, (long)S_ * SMP_);

    // head_out = (P_unnorm @ V) / rsum  (XCD-swizzled) -> cs reused
    gemm_k<5, 2><<<768, 256, 0, stream>>>(
        Pb, vtb, rsum, cs, nullptr, nullptr, SMP_, SMP_, D_, SMP_, D_,
        (long)S_ * SMP_, (long)D_ * SMP_, (long)S_ * D_);

    // out = head_out @ wo^T + bo (fp32)
    gemm_k<1, 3><<<dim3(6, 128), 256, 0, stream>>>(
        cs, wob, bo, d_out, nullptr, nullptr, D_, D_, D_, D_, D_, 0, 0, 0);
}